// Round 1
// baseline (553.475 us; speedup 1.0000x reference)
//
#include <hip/hip_runtime.h>
#include <hip/hip_bf16.h>

// Problem constants (from reference)
#define TT 128   // time points
#define DD 64    // state dim
#define HH 256   // f-net hidden
#define HK 128   // kernel-net hidden
#define JH (TT*HK)      // 16384 contraction dim for G1
#define HD (HK*DD)      // 8192

// ---------------------------------------------------------------------------
// A[i, j*HK+h] = w[i,j] * tanh(t_i*Wk1[0,h] + t_j*Wk1[1,h] + bk1[h])
// (iteration-invariant; dense incl. zeros for j>i and row i=0)
// ---------------------------------------------------------------------------
__global__ void k_A(const float* __restrict__ t, const float* __restrict__ Wk1,
                    const float* __restrict__ bk1, float* __restrict__ A) {
    int j = blockIdx.x, i = blockIdx.y, h = threadIdx.x;  // h in [0,128)
    float dt = t[1] - t[0];
    float w;
    if (i == 0 || j > i) w = 0.f;
    else w = dt * ((j == 0 || j == i) ? 0.5f : 1.0f);
    float v = tanhf(t[i] * Wk1[h] + t[j] * Wk1[HK + h] + bk1[h]);
    A[((size_t)i * TT + j) * HK + h] = w * v;
}

// ---------------------------------------------------------------------------
// Wk2t[e*HD + h*DD + d] = Wk2[h*DD*DD + d*DD + e]   (transpose for coalesced M GEMM)
// ---------------------------------------------------------------------------
__global__ void k_transpose_wk2(const float* __restrict__ Wk2, float* __restrict__ Wk2t) {
    __shared__ float s[64][65];
    int h = blockIdx.x;  // 128 blocks
    for (int k = threadIdx.x; k < DD * DD; k += 256) {
        int d = k >> 6, e = k & 63;
        s[d][e] = Wk2[(size_t)h * DD * DD + k];
    }
    __syncthreads();
    for (int k = threadIdx.x; k < DD * DD; k += 256) {
        int e = k >> 6, d = k & 63;
        Wk2t[(size_t)e * HD + h * DD + d] = s[d][e];
    }
}

// ---------------------------------------------------------------------------
// y_init[i,d] = z0[d]
// ---------------------------------------------------------------------------
__global__ void k_init_y(const float* __restrict__ z0, float* __restrict__ y) {
    int i = blockIdx.x, d = threadIdx.x;
    y[i * DD + d] = z0[d];
}

// ---------------------------------------------------------------------------
// F[j,:] = tanh(y[j,:] @ W1 + b1) @ W2 + b2 ;  bF[j,d] = sum_e bk2[d*DD+e]*F[j,e]
// one block per time point j, 256 threads
// ---------------------------------------------------------------------------
__global__ void k_f(const float* __restrict__ y, const float* __restrict__ W1,
                    const float* __restrict__ b1, const float* __restrict__ W2,
                    const float* __restrict__ b2, const float* __restrict__ bk2,
                    float* __restrict__ F, float* __restrict__ bF) {
    int j = blockIdx.x, t = threadIdx.x;
    __shared__ float ys[DD];
    __shared__ float hs[HH];
    __shared__ float fs[DD];
    if (t < DD) ys[t] = y[j * DD + t];
    __syncthreads();
    float acc = b1[t];
    #pragma unroll 8
    for (int e = 0; e < DD; ++e) acc += ys[e] * W1[e * HH + t];
    hs[t] = tanhf(acc);
    __syncthreads();
    if (t < DD) {
        float a = b2[t];
        #pragma unroll 8
        for (int h = 0; h < HH; ++h) a += hs[h] * W2[h * DD + t];
        fs[t] = a;
        F[j * DD + t] = a;
    }
    __syncthreads();
    if (t < DD) {
        float a = 0.f;
        #pragma unroll 8
        for (int e = 0; e < DD; ++e) a += bk2[t * DD + e] * fs[e];
        bF[j * DD + t] = a;
    }
}

// ---------------------------------------------------------------------------
// M[j*HD + hd] = sum_e F[j,e] * Wk2t[e*HD + hd]     ([128,64] @ [64,8192])
// grid: (32 hd-chunks of 256, 8 j-chunks of 16), 256 threads
// ---------------------------------------------------------------------------
__global__ void k_M(const float* __restrict__ F, const float* __restrict__ Wk2t,
                    float* __restrict__ M) {
    int t = threadIdx.x;
    int hd = blockIdx.x * 256 + t;
    int j0 = blockIdx.y * 16;
    __shared__ float Fs[16][DD];
    for (int k = t; k < 16 * DD; k += 256) Fs[k >> 6][k & 63] = F[j0 * DD + k];
    __syncthreads();
    float acc[16];
    #pragma unroll
    for (int k = 0; k < 16; ++k) acc[k] = 0.f;
    for (int e = 0; e < DD; ++e) {
        float wv = Wk2t[(size_t)e * HD + hd];
        #pragma unroll
        for (int k = 0; k < 16; ++k) acc[k] += Fs[k][e] * wv;
    }
    #pragma unroll
    for (int k = 0; k < 16; ++k) M[(size_t)(j0 + k) * HD + hd] = acc[k];
}

// ---------------------------------------------------------------------------
// Partial G1: P[c, i, d] = sum_{jh in chunk c} A[i, jh] * M[jh*DD + d]
// grid: (16 i-tiles of 8, 16 chunks of 1024), 256 threads (sub=t>>6, d=t&63)
// ---------------------------------------------------------------------------
__global__ void k_G1(const float* __restrict__ A, const float* __restrict__ M,
                     float* __restrict__ P) {
    __shared__ float As[8][1024];
    __shared__ float red[4][8][64];
    int itile = blockIdx.x, c = blockIdx.y;
    int t = threadIdx.x, sub = t >> 6, d = t & 63;
    for (int k = t; k < 8 * 1024; k += 256) {
        int r = k >> 10, jl = k & 1023;
        As[r][jl] = A[(size_t)(itile * 8 + r) * JH + c * 1024 + jl];
    }
    __syncthreads();
    float acc[8];
    #pragma unroll
    for (int r = 0; r < 8; ++r) acc[r] = 0.f;
    const float* Mp = M + (size_t)c * 1024 * DD + d;
    for (int jl = sub; jl < 1024; jl += 4) {
        float m = Mp[(size_t)jl * DD];
        #pragma unroll
        for (int r = 0; r < 8; ++r) acc[r] += As[r][jl] * m;
    }
    #pragma unroll
    for (int r = 0; r < 8; ++r) red[sub][r][d] = acc[r];
    __syncthreads();
    if (sub == 0) {
        #pragma unroll
        for (int r = 0; r < 8; ++r) {
            float v = red[0][r][d] + red[1][r][d] + red[2][r][d] + red[3][r][d];
            P[(size_t)c * (TT * DD) + (itile * 8 + r) * DD + d] = v;
        }
    }
}

// ---------------------------------------------------------------------------
// G[j,d] = sum_c P[c,j,d] + dt * (0.5*bF[0,d] + sum_{0<jp<j} bF[jp,d] + 0.5*bF[j,d])
// ---------------------------------------------------------------------------
__global__ void k_Gfin(const float* __restrict__ P, const float* __restrict__ bF,
                       const float* __restrict__ t, float* __restrict__ G) {
    int j = blockIdx.x, d = threadIdx.x;
    float dt = t[1] - t[0];
    float a = 0.f;
    #pragma unroll
    for (int c = 0; c < 16; ++c) a += P[(size_t)c * (TT * DD) + j * DD + d];
    if (j > 0) {
        float s = 0.5f * bF[d];
        for (int jp = 1; jp < j; ++jp) s += bF[jp * DD + d];
        s += 0.5f * bF[j * DD + d];
        a += dt * s;
    }
    G[j * DD + d] = a;
}

// ---------------------------------------------------------------------------
// y_new[i,d] = z0[d] + dt * (0.5*G[0,d] + sum_{0<j<i} G[j,d] + 0.5*G[i,d])
// last iteration: block i==T-1 also writes the final output
// ---------------------------------------------------------------------------
__global__ void k_ynew(const float* __restrict__ G, const float* __restrict__ z0,
                       const float* __restrict__ t, float* __restrict__ ynew,
                       float* __restrict__ out_final) {
    int i = blockIdx.x, d = threadIdx.x;
    float dt = t[1] - t[0];
    float a = 0.f;
    if (i > 0) {
        float s = 0.5f * G[d];
        for (int j = 1; j < i; ++j) s += G[j * DD + d];
        s += 0.5f * G[i * DD + d];
        a = dt * s;
    }
    float v = z0[d] + a;
    ynew[i * DD + d] = v;
    if (out_final != nullptr && i == TT - 1) out_final[d] = v;
}

extern "C" void kernel_launch(void* const* d_in, const int* in_sizes, int n_in,
                              void* d_out, int out_size, void* d_ws, size_t ws_size,
                              hipStream_t stream) {
    const float* z0  = (const float*)d_in[0];
    const float* t   = (const float*)d_in[1];
    const float* W1  = (const float*)d_in[2];
    const float* b1  = (const float*)d_in[3];
    const float* W2  = (const float*)d_in[4];
    const float* b2  = (const float*)d_in[5];
    const float* Wk1 = (const float*)d_in[6];
    const float* bk1 = (const float*)d_in[7];
    const float* Wk2 = (const float*)d_in[8];
    const float* bk2 = (const float*)d_in[9];
    float* out = (float*)d_out;

    float* ws   = (float*)d_ws;
    float* A    = ws;                       // T*T*HK      = 2,097,152
    float* Wk2t = A    + (size_t)TT*TT*HK;  // HK*D*D      =   524,288
    float* M    = Wk2t + (size_t)HK*DD*DD;  // T*HK*D      = 1,048,576
    float* F    = M    + (size_t)TT*HK*DD;  // T*D         =     8,192
    float* bF   = F    + TT*DD;             // T*D
    float* G    = bF   + TT*DD;             // T*D
    float* P    = G    + TT*DD;             // 16*T*D      =   131,072
    float* yA   = P    + 16*TT*DD;          // T*D
    float* yB   = yA   + TT*DD;             // T*D

    // iteration-invariant precompute
    k_A<<<dim3(TT, TT), HK, 0, stream>>>(t, Wk1, bk1, A);
    k_transpose_wk2<<<HK, 256, 0, stream>>>(Wk2, Wk2t);
    k_init_y<<<TT, DD, 0, stream>>>(z0, yA);

    float* ycur = yA;
    float* ynext = yB;
    for (int it = 0; it < 3; ++it) {
        k_f<<<TT, 256, 0, stream>>>(ycur, W1, b1, W2, b2, bk2, F, bF);
        k_M<<<dim3(HD / 256, TT / 16), 256, 0, stream>>>(F, Wk2t, M);
        k_G1<<<dim3(TT / 8, JH / 1024), 256, 0, stream>>>(A, M, P);
        k_Gfin<<<TT, DD, 0, stream>>>(P, bF, t, G);
        k_ynew<<<TT, DD, 0, stream>>>(G, z0, t, ynext, (it == 2) ? out : nullptr);
        float* tmp = ycur; ycur = ynext; ynext = tmp;
    }
}

// Round 2
// 249.451 us; speedup vs baseline: 2.2188x; 2.2188x over previous
//
#include <hip/hip_runtime.h>
#include <hip/hip_bf16.h>

// Problem constants (from reference)
#define TT 128   // time points
#define DD 64    // state dim
#define HH 256   // f-net hidden
#define HK 128   // kernel-net hidden
#define JH (TT*HK)      // 16384 contraction dim for G1
#define HD (HK*DD)      // 8192
#define NCHUNK 32       // jh chunks of 512 (= 4 j's each)

// ---------------------------------------------------------------------------
// A[i, j*HK+h] = w[i,j] * tanh(t_i*Wk1[0,h] + t_j*Wk1[1,h] + bk1[h])
// dense incl. zeros for j>i and row i=0 (zeros make triangular tiling easy)
// ---------------------------------------------------------------------------
__global__ void k_A(const float* __restrict__ t, const float* __restrict__ Wk1,
                    const float* __restrict__ bk1, float* __restrict__ A) {
    int j = blockIdx.x, i = blockIdx.y, h = threadIdx.x;  // h in [0,128)
    float dt = t[1] - t[0];
    float w;
    if (i == 0 || j > i) w = 0.f;
    else w = dt * ((j == 0 || j == i) ? 0.5f : 1.0f);
    float v = tanhf(t[i] * Wk1[h] + t[j] * Wk1[HK + h] + bk1[h]);
    A[((size_t)i * TT + j) * HK + h] = w * v;
}

// ---------------------------------------------------------------------------
// Wk2t[e*HD + h*DD + d] = Wk2[h*DD*DD + d*DD + e]
// ---------------------------------------------------------------------------
__global__ void k_transpose_wk2(const float* __restrict__ Wk2, float* __restrict__ Wk2t) {
    __shared__ float s[64][65];
    int h = blockIdx.x;  // 128 blocks
    for (int k = threadIdx.x; k < DD * DD; k += 256) {
        int d = k >> 6, e = k & 63;
        s[d][e] = Wk2[(size_t)h * DD * DD + k];
    }
    __syncthreads();
    for (int k = threadIdx.x; k < DD * DD; k += 256) {
        int e = k >> 6, d = k & 63;
        Wk2t[(size_t)e * HD + h * DD + d] = s[d][e];
    }
}

__global__ void k_init_y(const float* __restrict__ z0, float* __restrict__ y) {
    int i = blockIdx.x, d = threadIdx.x;
    y[i * DD + d] = z0[d];
}

// ---------------------------------------------------------------------------
// F[j,:] = tanh(y[j,:] @ W1 + b1) @ W2 + b2 ;  bF[j,d] = sum_e bk2[d*DD+e]*F[j,e]
// ---------------------------------------------------------------------------
__global__ void k_f(const float* __restrict__ y, const float* __restrict__ W1,
                    const float* __restrict__ b1, const float* __restrict__ W2,
                    const float* __restrict__ b2, const float* __restrict__ bk2,
                    float* __restrict__ F, float* __restrict__ bF) {
    int j = blockIdx.x, t = threadIdx.x;
    __shared__ float ys[DD];
    __shared__ float hs[HH];
    __shared__ float fs[DD];
    if (t < DD) ys[t] = y[j * DD + t];
    __syncthreads();
    float acc = b1[t];
    #pragma unroll 8
    for (int e = 0; e < DD; ++e) acc += ys[e] * W1[e * HH + t];
    hs[t] = tanhf(acc);
    __syncthreads();
    if (t < DD) {
        float a = b2[t];
        #pragma unroll 8
        for (int h = 0; h < HH; ++h) a += hs[h] * W2[h * DD + t];
        fs[t] = a;
        F[j * DD + t] = a;
    }
    __syncthreads();
    if (t < DD) {
        float a = 0.f;
        #pragma unroll 8
        for (int e = 0; e < DD; ++e) a += bk2[t * DD + e] * fs[e];
        bF[j * DD + t] = a;
    }
}

// ---------------------------------------------------------------------------
// M[j*HD + hd] = sum_e F[j,e] * Wk2t[e*HD + hd]     ([128,64] @ [64,8192])
// grid: (32 hd-chunks of 256, 8 j-chunks of 16), 256 threads
// batched loads: 8 Wk2t values in flight per trip
// ---------------------------------------------------------------------------
__global__ void k_M(const float* __restrict__ F, const float* __restrict__ Wk2t,
                    float* __restrict__ M) {
    int t = threadIdx.x;
    int hd = blockIdx.x * 256 + t;
    int j0 = blockIdx.y * 16;
    __shared__ __attribute__((aligned(16))) float Fs[16][64];
    for (int k = t; k < 16 * DD; k += 256) Fs[k >> 6][k & 63] = F[j0 * DD + k];
    __syncthreads();
    float acc[16];
    #pragma unroll
    for (int k = 0; k < 16; ++k) acc[k] = 0.f;
    const float* Wp = Wk2t + hd;
    for (int e = 0; e < DD; e += 8) {
        float w0 = Wp[(size_t)(e+0) * HD];
        float w1 = Wp[(size_t)(e+1) * HD];
        float w2 = Wp[(size_t)(e+2) * HD];
        float w3 = Wp[(size_t)(e+3) * HD];
        float w4 = Wp[(size_t)(e+4) * HD];
        float w5 = Wp[(size_t)(e+5) * HD];
        float w6 = Wp[(size_t)(e+6) * HD];
        float w7 = Wp[(size_t)(e+7) * HD];
        #pragma unroll
        for (int k = 0; k < 16; ++k) {
            float4 f0 = *(const float4*)&Fs[k][e];
            float4 f1 = *(const float4*)&Fs[k][e + 4];
            acc[k] += f0.x*w0 + f0.y*w1 + f0.z*w2 + f0.w*w3
                    + f1.x*w4 + f1.y*w5 + f1.z*w6 + f1.w*w7;
        }
    }
    #pragma unroll
    for (int k = 0; k < 16; ++k) M[(size_t)(j0 + k) * HD + hd] = acc[k];
}

// ---------------------------------------------------------------------------
// Partial G1: P[c, i, d] = sum_{jh in chunk c (512 wide)} A[i, jh] * M[jh*DD + d]
// grid: (16 i-tiles of 8, 32 chunks), 256 threads (sub=t>>6, d=t&63)
// triangular skip: chunk c covers j in [4c, 4c+4); zero unless 4c <= 8*it+7
// ---------------------------------------------------------------------------
__global__ void k_G1(const float* __restrict__ A, const float* __restrict__ M,
                     float* __restrict__ P) {
    int itile = blockIdx.x, c = blockIdx.y;
    if (c > 2 * itile + 1) return;   // entirely upper-triangle -> A tile all zero
    __shared__ __attribute__((aligned(16))) float As[8 * 512];   // 16 KB
    __shared__ float red[4][8][64];                              // 8 KB
    int t = threadIdx.x, sub = t >> 6, d = t & 63;
    {
        const float* Ab = A + (size_t)itile * 8 * JH + c * 512;
        float4* As4 = (float4*)As;
        #pragma unroll
        for (int k = 0; k < 4; ++k) {
            int idx = t + k * 256;            // 1024 float4 total
            int r = idx >> 7, q = idx & 127;
            As4[r * 128 + q] = *(const float4*)(Ab + (size_t)r * JH + q * 4);
        }
    }
    __syncthreads();
    float acc[8] = {0.f, 0.f, 0.f, 0.f, 0.f, 0.f, 0.f, 0.f};
    const float* Mp = M + ((size_t)c * 512) * DD + d;
    int jl0 = sub * 128;
    for (int jl = jl0; jl < jl0 + 128; jl += 8) {
        float m0 = Mp[(size_t)(jl + 0) * DD];
        float m1 = Mp[(size_t)(jl + 1) * DD];
        float m2 = Mp[(size_t)(jl + 2) * DD];
        float m3 = Mp[(size_t)(jl + 3) * DD];
        float m4 = Mp[(size_t)(jl + 4) * DD];
        float m5 = Mp[(size_t)(jl + 5) * DD];
        float m6 = Mp[(size_t)(jl + 6) * DD];
        float m7 = Mp[(size_t)(jl + 7) * DD];
        #pragma unroll
        for (int r = 0; r < 8; ++r) {
            float4 a0 = *(const float4*)&As[r * 512 + jl];
            float4 a1 = *(const float4*)&As[r * 512 + jl + 4];
            acc[r] += a0.x*m0 + a0.y*m1 + a0.z*m2 + a0.w*m3
                    + a1.x*m4 + a1.y*m5 + a1.z*m6 + a1.w*m7;
        }
    }
    #pragma unroll
    for (int r = 0; r < 8; ++r) red[sub][r][d] = acc[r];
    __syncthreads();
    if (sub == 0) {
        #pragma unroll
        for (int r = 0; r < 8; ++r) {
            float v = red[0][r][d] + red[1][r][d] + red[2][r][d] + red[3][r][d];
            P[(size_t)c * (TT * DD) + (itile * 8 + r) * DD + d] = v;
        }
    }
}

// ---------------------------------------------------------------------------
// G[j,d] = sum_{c<=j>>2} P[c,j,d] + dt * trapezoid(bF[0..j], d)
// predicated full-range loop -> unrollable, independent loads
// ---------------------------------------------------------------------------
__global__ void k_Gfin(const float* __restrict__ P, const float* __restrict__ bF,
                       const float* __restrict__ t, float* __restrict__ G) {
    int j = blockIdx.x, d = threadIdx.x;  // 64 threads
    float dt = t[1] - t[0];
    float a = 0.f;
    int cmax = j >> 2;
    #pragma unroll 8
    for (int c = 0; c <= cmax; ++c) a += P[(size_t)c * (TT * DD) + j * DD + d];
    if (j > 0) {
        float s = 0.f;
        #pragma unroll 8
        for (int jp = 0; jp <= j; ++jp) {
            float wgt = (jp == 0 || jp == j) ? 0.5f : 1.0f;
            s += wgt * bF[jp * DD + d];
        }
        a += dt * s;
    }
    G[j * DD + d] = a;
}

// ---------------------------------------------------------------------------
// y_new[i,d] = z0[d] + dt * trapezoid(G[0..i], d)
// ---------------------------------------------------------------------------
__global__ void k_ynew(const float* __restrict__ G, const float* __restrict__ z0,
                       const float* __restrict__ t, float* __restrict__ ynew,
                       float* __restrict__ out_final) {
    int i = blockIdx.x, d = threadIdx.x;
    float dt = t[1] - t[0];
    float a = 0.f;
    if (i > 0) {
        float s = 0.f;
        #pragma unroll 8
        for (int j = 0; j <= i; ++j) {
            float wgt = (j == 0 || j == i) ? 0.5f : 1.0f;
            s += wgt * G[j * DD + d];
        }
        a = dt * s;
    }
    float v = z0[d] + a;
    ynew[i * DD + d] = v;
    if (out_final != nullptr && i == TT - 1) out_final[d] = v;
}

extern "C" void kernel_launch(void* const* d_in, const int* in_sizes, int n_in,
                              void* d_out, int out_size, void* d_ws, size_t ws_size,
                              hipStream_t stream) {
    const float* z0  = (const float*)d_in[0];
    const float* t   = (const float*)d_in[1];
    const float* W1  = (const float*)d_in[2];
    const float* b1  = (const float*)d_in[3];
    const float* W2  = (const float*)d_in[4];
    const float* b2  = (const float*)d_in[5];
    const float* Wk1 = (const float*)d_in[6];
    const float* bk1 = (const float*)d_in[7];
    const float* Wk2 = (const float*)d_in[8];
    const float* bk2 = (const float*)d_in[9];
    float* out = (float*)d_out;

    float* ws   = (float*)d_ws;
    float* A    = ws;                       // T*T*HK        = 2,097,152
    float* Wk2t = A    + (size_t)TT*TT*HK;  // HK*D*D        =   524,288
    float* M    = Wk2t + (size_t)HK*DD*DD;  // T*HK*D        = 1,048,576
    float* F    = M    + (size_t)TT*HK*DD;  // T*D           =     8,192
    float* bF   = F    + TT*DD;             // T*D
    float* G    = bF   + TT*DD;             // T*D
    float* P    = G    + TT*DD;             // 32*T*D        =   262,144
    float* yA   = P    + (size_t)NCHUNK*TT*DD;
    float* yB   = yA   + TT*DD;

    // iteration-invariant precompute
    k_A<<<dim3(TT, TT), HK, 0, stream>>>(t, Wk1, bk1, A);
    k_transpose_wk2<<<HK, 256, 0, stream>>>(Wk2, Wk2t);
    k_init_y<<<TT, DD, 0, stream>>>(z0, yA);

    float* ycur = yA;
    float* ynext = yB;
    for (int it = 0; it < 3; ++it) {
        k_f<<<TT, 256, 0, stream>>>(ycur, W1, b1, W2, b2, bk2, F, bF);
        k_M<<<dim3(HD / 256, TT / 16), 256, 0, stream>>>(F, Wk2t, M);
        k_G1<<<dim3(TT / 8, NCHUNK), 256, 0, stream>>>(A, M, P);
        k_Gfin<<<TT, DD, 0, stream>>>(P, bF, t, G);
        k_ynew<<<TT, DD, 0, stream>>>(G, z0, t, ynext, (it == 2) ? out : nullptr);
        float* tmp = ycur; ycur = ynext; ynext = tmp;
    }
}